// Round 5
// baseline (500.967 us; speedup 1.0000x reference)
//
#include <hip/hip_runtime.h>

#define BB 16
#define SS 2048
#define DD 128
#define SCALE 0.08838834764831845f  // 1/sqrt(128)

typedef __attribute__((ext_vector_type(8))) short bf16x8;
typedef __attribute__((ext_vector_type(4))) float f32x4;
typedef __attribute__((ext_vector_type(16))) float f32x16;

__device__ __forceinline__ unsigned short f2bf(float f) {
    union { float f; unsigned int u; } v; v.f = f;
    unsigned int u = v.u;
    return (unsigned short)((u + 0x7fffu + ((u >> 16) & 1u)) >> 16);  // RNE
}

// ---- pre-pass 1: fp32 -> bf16 contiguous copy (used for Q and K) ----
__global__ __launch_bounds__(256) void cvt_bf16_kernel(const float* __restrict__ src,
                                                       unsigned short* __restrict__ dst) {
    int idx = (blockIdx.x * 256 + threadIdx.x) * 4;
    float4 f = *(const float4*)(src + idx);
    ushort4 o;
    o.x = f2bf(f.x); o.y = f2bf(f.y); o.z = f2bf(f.z); o.w = f2bf(f.w);
    *(ushort4*)(dst + idx) = o;
}

// ---- pre-pass 2: V [B][S][D] fp32 -> Vt [B][D][S] bf16 (transpose) ----
__global__ __launch_bounds__(256) void transpose_v_kernel(const float* __restrict__ v,
                                                          unsigned short* __restrict__ vt) {
    __shared__ unsigned short sT[64 * 132];
    int b = blockIdx.x >> 5;
    int s0 = (blockIdx.x & 31) * 64;
    int tid = threadIdx.x;
#pragma unroll
    for (int rnd = 0; rnd < 8; ++rnd) {
        int slot = rnd * 256 + tid;
        int row = slot >> 5;        // 0..63 (s)
        int c4 = (slot & 31) * 4;   // 0..124 (d)
        float4 f = *(const float4*)(v + (size_t)(b * SS + s0 + row) * DD + c4);
        unsigned short* p = &sT[row * 132 + c4];
        p[0] = f2bf(f.x); p[1] = f2bf(f.y); p[2] = f2bf(f.z); p[3] = f2bf(f.w);
    }
    __syncthreads();
#pragma unroll
    for (int rnd = 0; rnd < 4; ++rnd) {
        int slot = rnd * 256 + tid;
        int d = slot >> 3;          // 0..127
        int k8 = (slot & 7) * 8;    // 0..56
        __align__(16) unsigned short tmp[8];
#pragma unroll
        for (int e = 0; e < 8; ++e) tmp[e] = sT[(k8 + e) * 132 + d];
        *(ushort4*)(vt + (size_t)(b * DD + d) * SS + s0 + k8) = *(ushort4*)&tmp[0];
        *(ushort4*)(vt + (size_t)(b * DD + d) * SS + s0 + k8 + 4) = *(ushort4*)&tmp[4];
    }
}

// ---- main fused attention: one block per (b, 64-row q tile) ----
// Barrier-free main loops: K/V fragments read directly from L2 (data is
// L2-resident per XCD), P kept in registers via 32x32 MFMA layout + lane swap.
__global__ __launch_bounds__(256) void attn_kernel(const unsigned short* __restrict__ Qb,
                                                   const unsigned short* __restrict__ Kb,
                                                   const unsigned short* __restrict__ Vt,
                                                   const int* __restrict__ mask,
                                                   float* __restrict__ outO,
                                                   float* __restrict__ outA) {
    __shared__ float sO[64 * 132];    // 33 KB: epilogue O reduce scratch
    __shared__ float sLpart[2][64];
    __shared__ float sLinv[64];

    // XCD-aware swizzle: XCD x handles batches {2x, 2x+1} -> K/V/Q L2-resident
    int bi = blockIdx.x;
    int slot = bi >> 3;
    int b = (bi & 7) * 2 + (slot >> 5);
    int qt = slot & 31;

    int tid = threadIdx.x;
    int wave = tid >> 6, lane = tid & 63;
    const int q5 = lane & 31;          // 32x32 MFMA row/col index
    const int h = lane >> 5;           // half-wave index

    const int kq0 = (wave >> 1) * 32;  // wave's k quadrant (32 keys)
    const int qq0 = (wave & 1) * 32;   // wave's q quadrant (32 queries)

    // ---- Q fragments in registers for the whole kernel (8 x bf16x8 = 32 VGPR) ----
    // B-operand 32x32x16: col = q5, d-chunk = ks*16 + h*8 + e
    const unsigned short* Qlane = Qb + (size_t)(b * SS + qt * 64 + qq0 + q5) * DD + h * 8;
    bf16x8 qf[8];
#pragma unroll
    for (int ks = 0; ks < 8; ++ks) qf[ks] = *(const bf16x8*)(Qlane + ks * 16);

    // per-lane base pointers (loop-invariant)
    // K A-operand: row = kq0+q5, d-chunk = ks*16 + h*8
    const unsigned short* Klane = Kb + (size_t)b * SS * DD + (size_t)(kq0 + q5) * DD + h * 8;
    // V A-operand: row dv = dvt*32+q5, key-chunk = t*64 + kq0 + c*16 + h*8
    const unsigned short* Vlane = Vt + (size_t)b * DD * SS + (size_t)q5 * SS + kq0 + h * 8;
    const int* mlane = mask + (size_t)b * SS + kq0 + 4 * h;

    // ---------------- phase 1: row sums (no barriers, no LDS) ----------------
    float lsum = 0.f;
#pragma unroll 1
    for (int t = 0; t < 32; ++t) {
        bf16x8 af[8];
#pragma unroll
        for (int ks = 0; ks < 8; ++ks)
            af[ks] = *(const bf16x8*)(Klane + t * 8192 + ks * 16);
        int4 mm[4];
#pragma unroll
        for (int g = 0; g < 4; ++g)
            mm[g] = *(const int4*)(mlane + t * 64 + 8 * g);
        f32x16 acc;
#pragma unroll
        for (int i = 0; i < 16; ++i) acc[i] = 0.f;
        __builtin_amdgcn_s_setprio(1);
#pragma unroll
        for (int ks = 0; ks < 8; ++ks)
            acc = __builtin_amdgcn_mfma_f32_32x32x16_bf16(af[ks], qf[ks], acc, 0, 0, 0);
        __builtin_amdgcn_s_setprio(0);
        // lane holds S^T[k = 8*(r>>2)+(r&3)+4h + kq0][q = qq0+q5]
#pragma unroll
        for (int g = 0; g < 4; ++g) {
            float mv0 = mm[g].x ? 1.f : 0.f, mv1 = mm[g].y ? 1.f : 0.f;
            float mv2 = mm[g].z ? 1.f : 0.f, mv3 = mm[g].w ? 1.f : 0.f;
            lsum += __expf(acc[4 * g + 0] * SCALE) * mv0 + __expf(acc[4 * g + 1] * SCALE) * mv1 +
                    __expf(acc[4 * g + 2] * SCALE) * mv2 + __expf(acc[4 * g + 3] * SCALE) * mv3;
        }
    }
    lsum += __shfl_xor(lsum, 32);           // combine h halves (same q)
    if (lane < 32) sLpart[kq0 >> 5][qq0 + q5] = lsum;
    __syncthreads();
    if (tid < 64) sLinv[tid] = 1.f / (sLpart[0][tid] + sLpart[1][tid]);
    __syncthreads();
    const float linv = sLinv[qq0 + q5];

    // ---------------- phase 2: recompute S, write attn, O partial (no barriers) ----------------
    f32x16 oacc[4];   // [dvt]: O^T partial, row dv = dvt*32 + (reg&3)+8*(reg>>2)+4h, col q = q5
#pragma unroll
    for (int dvt = 0; dvt < 4; ++dvt)
#pragma unroll
        for (int i = 0; i < 16; ++i) oacc[dvt][i] = 0.f;

    float* Abase = outA + (size_t)(b * SS + qt * 64 + qq0 + q5) * SS + kq0 + 4 * h;

#pragma unroll 1
    for (int t = 0; t < 32; ++t) {
        bf16x8 af[8];
#pragma unroll
        for (int ks = 0; ks < 8; ++ks)
            af[ks] = *(const bf16x8*)(Klane + t * 8192 + ks * 16);
        bf16x8 vf[4][2];
#pragma unroll
        for (int dvt = 0; dvt < 4; ++dvt)
#pragma unroll
            for (int c = 0; c < 2; ++c)
                vf[dvt][c] = *(const bf16x8*)(Vlane + (size_t)dvt * 32 * SS + t * 64 + c * 16);
        int4 mm[4];
#pragma unroll
        for (int g = 0; g < 4; ++g)
            mm[g] = *(const int4*)(mlane + t * 64 + 8 * g);

        f32x16 acc;
#pragma unroll
        for (int i = 0; i < 16; ++i) acc[i] = 0.f;
        __builtin_amdgcn_s_setprio(1);
#pragma unroll
        for (int ks = 0; ks < 8; ++ks)
            acc = __builtin_amdgcn_mfma_f32_32x32x16_bf16(af[ks], qf[ks], acc, 0, 0, 0);
        __builtin_amdgcn_s_setprio(0);

        float p[16];
#pragma unroll
        for (int g = 0; g < 4; ++g) {
            float mv0 = mm[g].x ? 1.f : 0.f, mv1 = mm[g].y ? 1.f : 0.f;
            float mv2 = mm[g].z ? 1.f : 0.f, mv3 = mm[g].w ? 1.f : 0.f;
            p[4 * g + 0] = __expf(acc[4 * g + 0] * SCALE) * mv0 * linv;
            p[4 * g + 1] = __expf(acc[4 * g + 1] * SCALE) * mv1 * linv;
            p[4 * g + 2] = __expf(acc[4 * g + 2] * SCALE) * mv2 * linv;
            p[4 * g + 3] = __expf(acc[4 * g + 3] * SCALE) * mv3 * linv;
        }
        // outA: 4 x float4 stores, keys = t*64 + kq0 + 8g + 4h + {0..3}
#pragma unroll
        for (int g = 0; g < 4; ++g) {
            f32x4 st = {p[4 * g], p[4 * g + 1], p[4 * g + 2], p[4 * g + 3]};
            *(f32x4*)(Abase + t * 64 + 8 * g) = st;
        }
        // pack to bf16 words: pw[g][w] covers keys 8g+4h+{2w, 2w+1}
        unsigned pw[4][2];
#pragma unroll
        for (int g = 0; g < 4; ++g) {
            pw[g][0] = (unsigned)f2bf(p[4 * g]) | ((unsigned)f2bf(p[4 * g + 1]) << 16);
            pw[g][1] = (unsigned)f2bf(p[4 * g + 2]) | ((unsigned)f2bf(p[4 * g + 3]) << 16);
        }
        // build PV B-operand fragments: pfrag[c] holds k = c*16 + h*8 + e, col q5.
        // Lane h needs group g=2c+h: e0..3 from h'=0 lane, e4..7 from h'=1 lane.
        bf16x8 pfrag[2];
#pragma unroll
        for (int c = 0; c < 2; ++c) {
            unsigned s0 = h ? pw[2 * c][0] : pw[2 * c + 1][0];
            unsigned s1 = h ? pw[2 * c][1] : pw[2 * c + 1][1];
            unsigned r0 = (unsigned)__shfl_xor((int)s0, 32);
            unsigned r1 = (unsigned)__shfl_xor((int)s1, 32);
            union { unsigned u[4]; bf16x8 v; } pf;
            pf.u[0] = h ? r0 : pw[2 * c][0];
            pf.u[1] = h ? r1 : pw[2 * c][1];
            pf.u[2] = h ? pw[2 * c + 1][0] : r0;
            pf.u[3] = h ? pw[2 * c + 1][1] : r1;
            pfrag[c] = pf.v;
        }
        __builtin_amdgcn_s_setprio(1);
#pragma unroll
        for (int dvt = 0; dvt < 4; ++dvt)
#pragma unroll
            for (int c = 0; c < 2; ++c)
                oacc[dvt] = __builtin_amdgcn_mfma_f32_32x32x16_bf16(vf[dvt][c], pfrag[c], oacc[dvt], 0, 0, 0);
        __builtin_amdgcn_s_setprio(0);
    }

    // ---------------- epilogue: reduce wave pairs (0+2, 1+3) and store O ----------------
    __syncthreads();   // phase-2 done; sO free
    if (wave >= 2) {
#pragma unroll
        for (int dvt = 0; dvt < 4; ++dvt)
#pragma unroll
            for (int g = 0; g < 4; ++g) {
                f32x4 v = {oacc[dvt][4 * g], oacc[dvt][4 * g + 1],
                           oacc[dvt][4 * g + 2], oacc[dvt][4 * g + 3]};
                *(f32x4*)&sO[(qq0 + q5) * 132 + dvt * 32 + 8 * g + 4 * h] = v;
            }
    }
    __syncthreads();
    if (wave < 2) {
        float* Obase = outO + (size_t)(b * SS + qt * 64 + qq0 + q5) * DD;
#pragma unroll
        for (int dvt = 0; dvt < 4; ++dvt)
#pragma unroll
            for (int g = 0; g < 4; ++g) {
                int dv = dvt * 32 + 8 * g + 4 * h;
                f32x4 o = *(const f32x4*)&sO[(qq0 + q5) * 132 + dv];
                f32x4 v = {oacc[dvt][4 * g] + o[0], oacc[dvt][4 * g + 1] + o[1],
                           oacc[dvt][4 * g + 2] + o[2], oacc[dvt][4 * g + 3] + o[3]};
                *(f32x4*)(Obase + dv) = v;
            }
    }
}

extern "C" void kernel_launch(void* const* d_in, const int* in_sizes, int n_in,
                              void* d_out, int out_size, void* d_ws, size_t ws_size,
                              hipStream_t stream) {
    const float* Q = (const float*)d_in[0];
    const float* K = (const float*)d_in[1];
    const float* V = (const float*)d_in[2];
    const int* mask = (const int*)d_in[3];

    float* outO = (float*)d_out;                          // [B,S,D]
    float* outA = outO + (size_t)BB * SS * DD;            // [B,S,S]

    unsigned short* Qb = (unsigned short*)d_ws;           // bf16 [B,S,D]  8 MiB
    unsigned short* Kb = Qb + (size_t)BB * SS * DD;       // bf16 [B,S,D]  8 MiB
    unsigned short* Vt = Kb + (size_t)BB * SS * DD;       // bf16 [B,D,S]  8 MiB

    int nconv = (BB * SS * DD) / (256 * 4);               // 4096 blocks
    cvt_bf16_kernel<<<nconv, 256, 0, stream>>>(Q, Qb);
    cvt_bf16_kernel<<<nconv, 256, 0, stream>>>(K, Kb);
    transpose_v_kernel<<<BB * (SS / 64), 256, 0, stream>>>(V, Vt);
    attn_kernel<<<BB * (SS / 64), 256, 0, stream>>>(Qb, Kb, Vt, mask, outO, outA);
}